// Round 1
// baseline (509.767 us; speedup 1.0000x reference)
//
#include <hip/hip_runtime.h>
#include <math.h>

#define NEWTON_ITERS 14

// ---------------------------------------------------------------------------
// Kernel A: P = l2_normalize(X @ W^T + b) for both (sub, edge).
// grid (128, 2), block 256. Block = 64 rows x all 64 output cols, K=512 in
// 4 chunks of 128. Wave w handles column-quarter w (lanes = rows), so W
// reads from LDS are wave-uniform broadcasts.
// ---------------------------------------------------------------------------
__global__ __launch_bounds__(256) void proj_norm_kernel(
    const float* __restrict__ Xsub, const float* __restrict__ Xedge,
    const float* __restrict__ Wsub, const float* __restrict__ bsub,
    const float* __restrict__ Wedge, const float* __restrict__ bedge,
    float* __restrict__ Psub, float* __restrict__ Pedge)
{
    const int mat = blockIdx.y;
    const float* X  = mat ? Xedge : Xsub;
    const float* W  = mat ? Wedge : Wsub;
    const float* Bv = mat ? bedge : bsub;
    float* OUT      = mat ? Pedge : Psub;

    const int r0 = blockIdx.x * 64;
    const int t  = threadIdx.x;
    const int lr = t & 63;   // row within tile == lane id
    const int q  = t >> 6;   // wave id == column quarter
    const int c0 = q * 16;

    __shared__ float4 xs[64 * 33];   // [row][kc], 128 k per chunk = 32 f4 (+1 pad)
    __shared__ float4 wq[64 * 33];   // [c][kc]
    __shared__ float  red[4][64];

    float acc[16];
#pragma unroll
    for (int i = 0; i < 16; ++i) acc[i] = 0.0f;

    for (int ch = 0; ch < 4; ++ch) {
        const int kb = ch * 128;
#pragma unroll
        for (int i = 0; i < 8; ++i) {
            int e = t + 256 * i;          // 2048 float4 per tile
            int row = e >> 5, kc = e & 31;
            xs[row * 33 + kc] = *(const float4*)(X + (size_t)(r0 + row) * 512 + kb + kc * 4);
            wq[row * 33 + kc] = *(const float4*)(W + (size_t)row * 512 + kb + kc * 4);
        }
        __syncthreads();
#pragma unroll 4
        for (int kc = 0; kc < 32; ++kc) {
            const float4 x4 = xs[lr * 33 + kc];
#pragma unroll
            for (int cc = 0; cc < 16; ++cc) {
                const float4 w4 = wq[(c0 + cc) * 33 + kc];   // wave-uniform broadcast
                acc[cc] = fmaf(x4.x, w4.x, acc[cc]);
                acc[cc] = fmaf(x4.y, w4.y, acc[cc]);
                acc[cc] = fmaf(x4.z, w4.z, acc[cc]);
                acc[cc] = fmaf(x4.w, w4.w, acc[cc]);
            }
        }
        __syncthreads();
    }

    // bias + rowwise l2 normalize (n = sqrt(sum x^2); x / max(n, 1e-12))
    float ss = 0.0f;
#pragma unroll
    for (int cc = 0; cc < 16; ++cc) {
        acc[cc] += Bv[c0 + cc];
        ss = fmaf(acc[cc], acc[cc], ss);
    }
    red[q][lr] = ss;
    __syncthreads();
    const float tot = red[0][lr] + red[1][lr] + red[2][lr] + red[3][lr];
    const float inv = 1.0f / fmaxf(sqrtf(tot), 1e-12f);

    float* op = OUT + (size_t)(r0 + lr) * 64 + c0;
#pragma unroll
    for (int v = 0; v < 4; ++v) {
        float4 o;
        o.x = acc[v * 4 + 0] * inv;
        o.y = acc[v * 4 + 1] * inv;
        o.z = acc[v * 4 + 2] * inv;
        o.w = acc[v * 4 + 3] * inv;
        *(float4*)(op + v * 4) = o;
    }
}

// ---------------------------------------------------------------------------
// Kernel B: Z[s][e] = (Psub[s] . Pedge[e]) * scale * 0.5  (z = scores/2)
// grid (64, 64), block 256. 128x128 tile, K=64 fully staged in LDS (k-major,
// pad 132 -> conflict-free b128 reads), 8x8 register micro-tile.
// ---------------------------------------------------------------------------
__global__ __launch_bounds__(256) void scores_kernel(
    const float* __restrict__ Psub, const float* __restrict__ Pedge,
    const float* __restrict__ log_scale, float* __restrict__ Z)
{
    __shared__ float la[64 * 132];
    __shared__ float lb[64 * 132];
    const int t  = threadIdx.x;
    const int m0 = blockIdx.y * 128;
    const int n0 = blockIdx.x * 128;

#pragma unroll
    for (int i = 0; i < 8; ++i) {
        int e = t + 256 * i;          // 2048 float4 per operand
        int m = e & 127, kq = e >> 7; // lanes span m -> conflict-free LDS writes
        float4 va = *(const float4*)(Psub + (size_t)(m0 + m) * 64 + kq * 4);
        la[(kq * 4 + 0) * 132 + m] = va.x;
        la[(kq * 4 + 1) * 132 + m] = va.y;
        la[(kq * 4 + 2) * 132 + m] = va.z;
        la[(kq * 4 + 3) * 132 + m] = va.w;
        float4 vb = *(const float4*)(Pedge + (size_t)(n0 + m) * 64 + kq * 4);
        lb[(kq * 4 + 0) * 132 + m] = vb.x;
        lb[(kq * 4 + 1) * 132 + m] = vb.y;
        lb[(kq * 4 + 2) * 132 + m] = vb.z;
        lb[(kq * 4 + 3) * 132 + m] = vb.w;
    }
    __syncthreads();

    const int tx = t & 15, ty = t >> 4;
    float acc[8][8] = {};

#pragma unroll 8
    for (int k = 0; k < 64; ++k) {
        const float4 a0 = *(const float4*)&la[k * 132 + ty * 4];
        const float4 a1 = *(const float4*)&la[k * 132 + ty * 4 + 64];
        const float4 b0 = *(const float4*)&lb[k * 132 + tx * 4];
        const float4 b1 = *(const float4*)&lb[k * 132 + tx * 4 + 64];
        const float av[8] = {a0.x, a0.y, a0.z, a0.w, a1.x, a1.y, a1.z, a1.w};
        const float bv[8] = {b0.x, b0.y, b0.z, b0.w, b1.x, b1.y, b1.z, b1.w};
#pragma unroll
        for (int i = 0; i < 8; ++i)
#pragma unroll
            for (int j = 0; j < 8; ++j)
                acc[i][j] = fmaf(av[i], bv[j], acc[i][j]);
    }

    float sc = expf(log_scale[0]);
    sc = fminf(fmaxf(sc, 0.5f), 20.0f);
    const float zs = sc * 0.5f;

#pragma unroll
    for (int i = 0; i < 8; ++i) {
        const int rl = (i < 4) ? (ty * 4 + i) : (64 + ty * 4 + (i - 4));
        float* rp = Z + (size_t)(m0 + rl) * 8192 + n0;
        float4 o0, o1;
        o0.x = acc[i][0] * zs; o0.y = acc[i][1] * zs;
        o0.z = acc[i][2] * zs; o0.w = acc[i][3] * zs;
        o1.x = acc[i][4] * zs; o1.y = acc[i][5] * zs;
        o1.z = acc[i][6] * zs; o1.w = acc[i][7] * zs;
        *(float4*)(rp + tx * 4)      = o0;
        *(float4*)(rp + tx * 4 + 64) = o1;
    }
}

// ---------------------------------------------------------------------------
// Kernel C: rowwise exact 1.5-entmax, in place on Z.
// tau solves sum(max(z - tau, 0)^2) = 1 (unique root). Newton from
// tau0 = zmax - 1 is monotone increasing (f convex decreasing) -> no
// overshoot; 14 fixed iterations (quadratic terminal convergence).
// One block (256 thr) per row; 32 z's per thread held in registers.
// ---------------------------------------------------------------------------
__global__ __launch_bounds__(256) void entmax_kernel(float* __restrict__ Z)
{
    const int row = blockIdx.x;
    const int t   = threadIdx.x;
    float* rp = Z + (size_t)row * 8192;

    float4 v[8];
#pragma unroll
    for (int j = 0; j < 8; ++j)
        v[j] = *(const float4*)(rp + t * 4 + 1024 * j);

    // block max
    float m = -1e30f;
#pragma unroll
    for (int j = 0; j < 8; ++j)
        m = fmaxf(m, fmaxf(fmaxf(v[j].x, v[j].y), fmaxf(v[j].z, v[j].w)));
#pragma unroll
    for (int off = 32; off; off >>= 1)
        m = fmaxf(m, __shfl_xor(m, off, 64));

    __shared__ float rmax[4];
    __shared__ float rf[NEWTON_ITERS][4];
    __shared__ float rg[NEWTON_ITERS][4];
    const int wid = t >> 6;
    if ((t & 63) == 0) rmax[wid] = m;
    __syncthreads();
    m = fmaxf(fmaxf(rmax[0], rmax[1]), fmaxf(rmax[2], rmax[3]));

    float tau = m - 1.0f;   // f(tau0) >= 1 guaranteed (max element contributes 1)

    for (int it = 0; it < NEWTON_ITERS; ++it) {
        float f = 0.0f, g = 0.0f;
#pragma unroll
        for (int j = 0; j < 8; ++j) {
            float d;
            d = fmaxf(v[j].x - tau, 0.0f); f = fmaf(d, d, f); g += d;
            d = fmaxf(v[j].y - tau, 0.0f); f = fmaf(d, d, f); g += d;
            d = fmaxf(v[j].z - tau, 0.0f); f = fmaf(d, d, f); g += d;
            d = fmaxf(v[j].w - tau, 0.0f); f = fmaf(d, d, f); g += d;
        }
#pragma unroll
        for (int off = 32; off; off >>= 1) {
            f += __shfl_xor(f, off, 64);
            g += __shfl_xor(g, off, 64);
        }
        if ((t & 63) == 0) { rf[it][wid] = f; rg[it][wid] = g; }
        __syncthreads();
        f = rf[it][0] + rf[it][1] + rf[it][2] + rf[it][3];
        g = rg[it][0] + rg[it][1] + rg[it][2] + rg[it][3];
        // g >= m - tau > 0 always (tau stays strictly below zmax)
        tau += (f - 1.0f) / (2.0f * g);
    }

#pragma unroll
    for (int j = 0; j < 8; ++j) {
        float4 o; float d;
        d = fmaxf(v[j].x - tau, 0.0f); o.x = d * d;
        d = fmaxf(v[j].y - tau, 0.0f); o.y = d * d;
        d = fmaxf(v[j].z - tau, 0.0f); o.z = d * d;
        d = fmaxf(v[j].w - tau, 0.0f); o.w = d * d;
        *(float4*)(rp + t * 4 + 1024 * j) = o;
    }
}

// ---------------------------------------------------------------------------
extern "C" void kernel_launch(void* const* d_in, const int* in_sizes, int n_in,
                              void* d_out, int out_size, void* d_ws, size_t ws_size,
                              hipStream_t stream)
{
    const float* edge_repr = (const float*)d_in[0];
    const float* sub_repr  = (const float*)d_in[1];
    const float* W_sub     = (const float*)d_in[2];
    const float* b_sub     = (const float*)d_in[3];
    const float* W_edge    = (const float*)d_in[4];
    const float* b_edge    = (const float*)d_in[5];
    const float* log_scale = (const float*)d_in[6];
    float* out = (float*)d_out;

    float* sub_proj  = (float*)d_ws;                    // 8192*64 fp32 = 2 MB
    float* edge_proj = (float*)d_ws + (size_t)8192 * 64; // next 2 MB

    proj_norm_kernel<<<dim3(128, 2), 256, 0, stream>>>(
        sub_repr, edge_repr, W_sub, b_sub, W_edge, b_edge, sub_proj, edge_proj);

    scores_kernel<<<dim3(64, 64), 256, 0, stream>>>(
        sub_proj, edge_proj, log_scale, out);

    entmax_kernel<<<8192, 256, 0, stream>>>(out);
}